// Round 2
// baseline (862.521 us; speedup 1.0000x reference)
//
#include <hip/hip_runtime.h>
#include <math.h>

#define BB 256
#define TT 512
#define KK 128

// padded LDS index: +4 floats per 32 to break bank wrap
#define AIDX(i) ((i) + (((i) >> 5) << 2))

typedef float v2f __attribute__((ext_vector_type(2)));

template<int CTRL>
__device__ __forceinline__ int dpp_i(int x) {
  return __builtin_amdgcn_update_dpp(x, x, CTRL, 0xF, 0xF, true);
}
template<int CTRL>
__device__ __forceinline__ float dpp_f(float x) {
  return __int_as_float(dpp_i<CTRL>(__float_as_int(x)));
}
template<int IMM>
__device__ __forceinline__ int swz_i(int x) { return __builtin_amdgcn_ds_swizzle(x, IMM); }
template<int IMM>
__device__ __forceinline__ float swz_f(float x) { return __int_as_float(swz_i<IMM>(__float_as_int(x))); }

// DPP ctrl: quad_perm[1,0,3,2]=0xB1 (xor1), quad_perm[2,3,0,1]=0x4E (xor2),
// row_mirror=0x140 (xor15; == xor8 under 8-lane replication)
// ds_swizzle BitMode: xor4=0x101F, xor16=0x401F

__global__ __launch_bounds__(512, 1) void crf_forward(
    const float* __restrict__ logits,     // [B,T,K]
    const int* __restrict__ labels,       // [B,T]
    const int* __restrict__ seq_lens,     // [B]
    const float* __restrict__ trans,      // [K,K]
    float* __restrict__ pred_out,         // [B,T] as float (d_out+1)
    float* __restrict__ negll,            // [B] in ws
    unsigned char* __restrict__ bp)       // [B,T,K] backpointers in ws
{
  const int b = blockIdx.x;
  const int tid = threadIdx.x;
  const int cg = tid >> 3;       // column-group 0..63 (2 cols each)
  const int rg = tid & 7;        // row-group 0..7 (16 rows each)
  const int j0 = cg * 2;
  const int i0 = rg * 16;
  const int L = seq_lens[b];

  __shared__ __align__(16) float avb[2][144];   // viterbi alpha, double-buffered
  __shared__ __align__(16) float evb[2][144];   // scaled forward probs
  __shared__ __align__(16) float wmax[16];      // per-32-lane-group ev maxes
  __shared__ unsigned char tags[TT];
  __shared__ float rv[8]; __shared__ int ri[8];
  __shared__ float rs[8]; __shared__ float rsc[8];
  __shared__ int last_s;

  // trans regs: row i0+ii, cols (j0, j0+1); raw for viterbi, exp for log-norm
  v2f tv[16], tw[16];
#pragma unroll
  for (int ii = 0; ii < 16; ++ii) {
    v2f tr = *(const v2f*)&trans[(i0 + ii) * KK + j0];
    tv[ii] = tr;
    tw[ii].x = __expf(tr.x);
    tw[ii].y = __expf(tr.y);
  }

  if (tid < KK) {
    float l0 = logits[(b * TT) * KK + tid];
    avb[0][AIDX(tid)] = l0;
    evb[0][AIDX(tid)] = __expf(l0);
  }
  if (tid < 16) wmax[tid] = 1.0f;

  v2f em_next = {0.0f, 0.0f};
  if (L > 1) em_next = *(const v2f*)&logits[(b * TT + 1) * KK + j0];
  __syncthreads();

  float Cln = 0.0f;              // accumulated log-scale (uniform)
  unsigned int bp_pend = 0;      // deferred bp store (packed 2 bytes)
  int bp_t = 0;

  for (int t = 1; t < L; ++t) {
    // deferred bp store from previous step: full body to complete before barrier
    if (rg == 0 && bp_t) {
      *(unsigned short*)(bp + (b * TT + bp_t) * KK + j0) = (unsigned short)bp_pend;
    }
    v2f em2 = em_next;           // emit for this step (prefetched)
    if (t + 1 < L) em_next = *(const v2f*)&logits[(b * TT + t + 1) * KK + j0];

    float r = 1.0f;
    if ((t & 3) == 1) {          // renorm every 4 steps (exact pow2 scale)
      float4 w0 = *(const float4*)&wmax[0];
      float4 w1 = *(const float4*)&wmax[4];
      float4 w2 = *(const float4*)&wmax[8];
      float4 w3 = *(const float4*)&wmax[12];
      float U = fmaxf(fmaxf(fmaxf(w0.x, w0.y), fmaxf(w0.z, w0.w)),
                      fmaxf(fmaxf(w1.x, w1.y), fmaxf(w1.z, w1.w)));
      U = fmaxf(U, fmaxf(fmaxf(fmaxf(w2.x, w2.y), fmaxf(w2.z, w2.w)),
                         fmaxf(fmaxf(w3.x, w3.y), fmaxf(w3.z, w3.w))));
      int ex = (__float_as_int(U) >> 23) & 255;
      r = __int_as_float((254 - ex) << 23);
      Cln += (float)(ex - 127) * 0.6931471805599453f;
    }

    const float* avp = avb[(t & 1) ^ 1];
    const float* evp = evb[(t & 1) ^ 1];

    float mv0 = -3.4e38f, mv1 = -3.4e38f;
    int ai0 = 0, ai1 = 0;
    v2f S2 = {0.0f, 0.0f};
    const float4* avr = (const float4*)(avp + AIDX(i0));
    const float4* evr = (const float4*)(evp + AIDX(i0));
#pragma unroll
    for (int q = 0; q < 4; ++q) {
      float4 a4 = avr[q];
      float4 e4 = evr[q];
#pragma unroll
      for (int c = 0; c < 4; ++c) {
        float a = (c == 0) ? a4.x : (c == 1) ? a4.y : (c == 2) ? a4.z : a4.w;
        float e = (c == 0) ? e4.x : (c == 1) ? e4.y : (c == 2) ? e4.z : e4.w;
        const int idx = q * 4 + c;
        v2f s2 = (v2f){a, a} + tv[idx];          // IEEE fp32 adds (pk_add)
        if (s2.x > mv0) { mv0 = s2.x; ai0 = i0 + idx; }
        if (s2.y > mv1) { mv1 = s2.y; ai1 = i0 + idx; }
        S2 += (v2f){e, e} * tw[idx];             // pk_fma
      }
    }
    // combine across 8 row-groups: xor1 (DPP), xor2 (DPP), xor4 (swizzle)
    {
      float pm0 = dpp_f<0xB1>(mv0), pm1 = dpp_f<0xB1>(mv1);
      int   pa0 = dpp_i<0xB1>(ai0), pa1 = dpp_i<0xB1>(ai1);
      float px  = dpp_f<0xB1>(S2.x), py = dpp_f<0xB1>(S2.y);
      if (pm0 > mv0 || (pm0 == mv0 && pa0 < ai0)) { mv0 = pm0; ai0 = pa0; }
      if (pm1 > mv1 || (pm1 == mv1 && pa1 < ai1)) { mv1 = pm1; ai1 = pa1; }
      S2.x += px; S2.y += py;
    }
    {
      float pm0 = dpp_f<0x4E>(mv0), pm1 = dpp_f<0x4E>(mv1);
      int   pa0 = dpp_i<0x4E>(ai0), pa1 = dpp_i<0x4E>(ai1);
      float px  = dpp_f<0x4E>(S2.x), py = dpp_f<0x4E>(S2.y);
      if (pm0 > mv0 || (pm0 == mv0 && pa0 < ai0)) { mv0 = pm0; ai0 = pa0; }
      if (pm1 > mv1 || (pm1 == mv1 && pa1 < ai1)) { mv1 = pm1; ai1 = pa1; }
      S2.x += px; S2.y += py;
    }
    {
      float pm0 = swz_f<0x101F>(mv0), pm1 = swz_f<0x101F>(mv1);
      int   pa0 = swz_i<0x101F>(ai0), pa1 = swz_i<0x101F>(ai1);
      float px  = swz_f<0x101F>(S2.x), py = swz_f<0x101F>(S2.y);
      if (pm0 > mv0 || (pm0 == mv0 && pa0 < ai0)) { mv0 = pm0; ai0 = pa0; }
      if (pm1 > mv1 || (pm1 == mv1 && pa1 < ai1)) { mv1 = pm1; ai1 = pa1; }
      S2.x += px; S2.y += py;
    }

    // phase B: all 8 rg lanes now hold identical final (mv, ai, S) per column
    float evn0 = S2.x * __expf(em2.x) * r;
    float evn1 = S2.y * __expf(em2.y) * r;
    float* avw = avb[t & 1];
    float* evw = evb[t & 1];
    if (rg == 0) {
      *(v2f*)(avw + AIDX(j0)) = (v2f){mv0 + em2.x, mv1 + em2.y};
      *(v2f*)(evw + AIDX(j0)) = (v2f){evn0, evn1};
    }
    bp_pend = (unsigned int)ai0 | ((unsigned int)ai1 << 8);
    bp_t = t;

    if ((t & 3) == 0) {          // wmax only needed on renorm steps
      float wm = fmaxf(evn0, evn1);
      wm = fmaxf(wm, dpp_f<0x140>(wm));     // row_mirror: xor8 under replication
      wm = fmaxf(wm, swz_f<0x401F>(wm));    // xor16
      if ((tid & 31) == 0) wmax[tid >> 5] = wm;
    }
    __syncthreads();             // single barrier per step (double-buffered)
  }
  if (rg == 0 && bp_t) {         // flush final bp row
    *(unsigned short*)(bp + (b * TT + bp_t) * KK + j0) = (unsigned short)bp_pend;
  }

  const float* avf = avb[(L - 1) & 1];
  const float* evf = evb[(L - 1) & 1];

  // ---- final argmax (viterbi 'last'), ev sum (log_norm), sequence score ----
  {
    float v = (tid < KK) ? avf[AIDX(tid)] : -3.4e38f;
    int idx = (tid < KK) ? tid : KK;
#pragma unroll
    for (int m = 1; m < 64; m <<= 1) {
      float ov = __shfl_xor(v, m);
      int oi = __shfl_xor(idx, m);
      if (ov > v || (ov == v && oi < idx)) { v = ov; idx = oi; }
    }
    if ((tid & 63) == 0) { rv[tid >> 6] = v; ri[tid >> 6] = idx; }
  }
  {
    float s = (tid < KK) ? evf[AIDX(tid)] : 0.0f;
#pragma unroll
    for (int m = 1; m < 64; m <<= 1) s += __shfl_xor(s, m);
    if ((tid & 63) == 0) rs[tid >> 6] = s;
  }
  float sc = 0.0f;
  for (int tt2 = tid; tt2 < L; tt2 += 512) {
    int lab = labels[b * TT + tt2];
    sc += logits[(b * TT + tt2) * KK + lab];
    if (tt2 >= 1) sc += trans[labels[b * TT + tt2 - 1] * KK + lab];
  }
#pragma unroll
  for (int m = 1; m < 64; m <<= 1) sc += __shfl_xor(sc, m);
  if ((tid & 63) == 0) rsc[tid >> 6] = sc;
  __syncthreads();

  if (tid == 0) {
    float bv = rv[0]; int bi = ri[0];
    float es = rs[0]; float scf = rsc[0];
#pragma unroll
    for (int w = 1; w < 8; ++w) {
      if (rv[w] > bv || (rv[w] == bv && ri[w] < bi)) { bv = rv[w]; bi = ri[w]; }
      es += rs[w]; scf += rsc[w];
    }
    last_s = bi;
    float log_norm = Cln + logf(es);
    negll[b] = log_norm - scf;
  }
  __syncthreads();

  const int last = last_s;
  if (tid >= L - 1) tags[tid] = (unsigned char)last;
  __syncthreads();

  // ---- backtrace by wave 0: chunked row prefetch + shfl extraction ----
  if (tid < 64) {
    const int lane = tid;
    int tag = last;
    int t = L - 1;
    while (t >= 1) {
      const int nch = (t < 8) ? t : 8;
      unsigned short rows[8];
#pragma unroll
      for (int c = 0; c < 8; ++c) {
        if (c < nch)
          rows[c] = ((const unsigned short*)(bp + (b * TT + (t - c)) * KK))[lane];
      }
#pragma unroll
      for (int c = 0; c < 8; ++c) {
        if (c < nch) {
          int vrow = __shfl((int)rows[c], tag >> 1);
          tag = (vrow >> ((tag & 1) * 8)) & 255;
          if (lane == 0) tags[t - c - 1] = (unsigned char)tag;
        }
      }
      t -= nch;
    }
  }
  __syncthreads();

  pred_out[b * TT + tid] = (float)tags[tid];
}

__global__ void crf_loss_reduce(const float* __restrict__ negll, float* __restrict__ out) {
  int tid = threadIdx.x;
  float v = negll[tid];
#pragma unroll
  for (int m = 1; m < 64; m <<= 1) v += __shfl_xor(v, m);
  __shared__ float p[4];
  if ((tid & 63) == 0) p[tid >> 6] = v;
  __syncthreads();
  if (tid == 0) out[0] = p[0] + p[1] + p[2] + p[3];
}

extern "C" void kernel_launch(void* const* d_in, const int* in_sizes, int n_in,
                              void* d_out, int out_size, void* d_ws, size_t ws_size,
                              hipStream_t stream) {
  const float* logits   = (const float*)d_in[0];
  const int*   labels   = (const int*)d_in[1];
  const int*   seq_lens = (const int*)d_in[2];
  const float* trans    = (const float*)d_in[3];
  float* out = (float*)d_out;

  float* negll = (float*)d_ws;                          // 256 floats
  unsigned char* bp = (unsigned char*)d_ws + 1024;      // B*T*K bytes = 16.8 MB

  crf_forward<<<BB, 512, 0, stream>>>(logits, labels, seq_lens, trans,
                                      out + 1, negll, bp);
  crf_loss_reduce<<<1, 256, 0, stream>>>(negll, out);
}

// Round 3
// 701.151 us; speedup vs baseline: 1.2302x; 1.2302x over previous
//
#include <hip/hip_runtime.h>
#include <math.h>

#define BB 256
#define TT 512
#define KK 128

// padded LDS index: +4 floats per 32 to break bank wrap
#define AIDX(i) ((i) + (((i) >> 5) << 2))

typedef float v2f __attribute__((ext_vector_type(2)));

template<int CTRL>
__device__ __forceinline__ int dpp_i(int x) {
  return __builtin_amdgcn_update_dpp(x, x, CTRL, 0xF, 0xF, true);
}
template<int CTRL>
__device__ __forceinline__ float dpp_f(float x) {
  return __int_as_float(dpp_i<CTRL>(__float_as_int(x)));
}
__device__ __forceinline__ float swz16_f(float x) {
  return __int_as_float(__builtin_amdgcn_ds_swizzle(__float_as_int(x), 0x401F));
}

// DPP ctrl: 0xB1 quad_perm xor1, 0x4E quad_perm xor2,
// 0x141 row_half_mirror (==xor4 when quad-uniform), 0x140 row_mirror (==xor8 when 8-uniform)

__global__ __launch_bounds__(512, 1) void crf_forward(
    const float* __restrict__ logits,     // [B,T,K]
    const int* __restrict__ labels,       // [B,T]
    const int* __restrict__ seq_lens,     // [B]
    const float* __restrict__ trans,      // [K,K]
    float* __restrict__ pred_out,         // [B,T] as float (d_out+1)
    float* __restrict__ negll,            // [B] in ws
    unsigned char* __restrict__ bp)       // [B][64 chunks][64 cg][16B] in ws
{
  const int b = blockIdx.x;
  const int tid = threadIdx.x;
  const int cg = tid >> 3;       // column-group 0..63 (2 cols each)
  const int rg = tid & 7;        // row-group 0..7 (16 rows each)
  const int j0 = cg * 2;
  const int i0 = rg * 16;
  const int L = seq_lens[b];

  __shared__ __align__(16) float avb[2][144];
  __shared__ __align__(16) float evb[2][144];
  __shared__ __align__(16) float wmax[16];
  __shared__ unsigned char tags[TT];
  __shared__ float rv[8]; __shared__ int ri[8];
  __shared__ float rs[8]; __shared__ float rsc[8];
  __shared__ int last_s;

  // trans regs: rows i0..i0+15, cols (j0, j0+1)
  v2f tv[16], tw[16];
#pragma unroll
  for (int ii = 0; ii < 16; ++ii) {
    v2f tr = *(const v2f*)&trans[(i0 + ii) * KK + j0];
    tv[ii] = tr;
    tw[ii].x = __expf(tr.x);
    tw[ii].y = __expf(tr.y);
  }

  if (tid < KK) {
    float l0 = logits[(b * TT) * KK + tid];
    avb[0][AIDX(tid)] = l0;
    evb[0][AIDX(tid)] = __expf(l0);
  }
  if (tid < 16) wmax[tid] = 1.0f;

  // emit chunk registers: emC = current chunk (steps tc..tc+7), emN = next
  v2f emC[8], emN[8];
#pragma unroll
  for (int s = 0; s < 8; ++s) {
    int t2 = 1 + s; if (t2 > L - 1) t2 = (L > 1) ? (L - 1) : 0;
    emC[s] = *(const v2f*)&logits[(b * TT + t2) * KK + j0];
  }
  __syncthreads();

  float Cln = 0.0f;
  unsigned int pq0 = 0, pq1 = 0, pq2 = 0, pq3 = 0;   // pending bp chunk
  int pend_c = -1;

  for (int tc = 1; tc < L; tc += 8) {
    // issue next-chunk emit loads (drained at this chunk's first barrier)
#pragma unroll
    for (int s = 0; s < 8; ++s) {
      int t2 = tc + 8 + s; if (t2 > L - 1) t2 = L - 1;
      emN[s] = *(const v2f*)&logits[(b * TT + t2) * KK + j0];
    }
    // store previous chunk's backpointers (one dwordx4 per cg, rg==1 replica)
    if (pend_c >= 0 && rg == 1) {
      uint4 v; v.x = pq0; v.y = pq1; v.z = pq2; v.w = pq3;
      *(uint4*)(bp + ((((b << 6) + pend_c) << 6) + cg) * 16) = v;
    }
    unsigned int bq0 = 0, bq1 = 0, bq2 = 0, bq3 = 0;

#pragma unroll
    for (int s = 0; s < 8; ++s) {
      const int t = tc + s;
      if (t >= L) break;                 // uniform across block

      float r = 1.0f;
      if (s == 0 || s == 4) {            // renorm read (every 4 steps)
        float4 w0 = *(const float4*)&wmax[0];
        float4 w1 = *(const float4*)&wmax[4];
        float4 w2 = *(const float4*)&wmax[8];
        float4 w3 = *(const float4*)&wmax[12];
        float U = fmaxf(fmaxf(fmaxf(w0.x, w0.y), fmaxf(w0.z, w0.w)),
                        fmaxf(fmaxf(w1.x, w1.y), fmaxf(w1.z, w1.w)));
        U = fmaxf(U, fmaxf(fmaxf(fmaxf(w2.x, w2.y), fmaxf(w2.z, w2.w)),
                           fmaxf(fmaxf(w3.x, w3.y), fmaxf(w3.z, w3.w))));
        int ex = (__float_as_int(U) >> 23) & 255;
        r = __int_as_float((254 - ex) << 23);
        Cln += (float)(ex - 127) * 0.6931471805599453f;
      }

      const float* avp = avb[(t & 1) ^ 1];
      const float* evp = evb[(t & 1) ^ 1];
      const float4* avr = (const float4*)(avp + AIDX(i0));
      const float4* evr = (const float4*)(evp + AIDX(i0));

      // viterbi scores (exact IEEE adds) + forward FMAs
      v2f sv[16];
      v2f S2 = {0.0f, 0.0f};
#pragma unroll
      for (int q = 0; q < 4; ++q) {
        float4 a4 = avr[q];
        float4 e4 = evr[q];
#pragma unroll
        for (int c = 0; c < 4; ++c) {
          float a = (c == 0) ? a4.x : (c == 1) ? a4.y : (c == 2) ? a4.z : a4.w;
          float e = (c == 0) ? e4.x : (c == 1) ? e4.y : (c == 2) ? e4.z : e4.w;
          const int idx = q * 4 + c;
          sv[idx] = (v2f){a, a} + tv[idx];
          S2 += (v2f){e, e} * tw[idx];
        }
      }
      // max tree (exact), then first-index recovery scan
      v2f m;
      {
        v2f m0 = __builtin_elementwise_max(sv[0], sv[1]);
        v2f m1 = __builtin_elementwise_max(sv[2], sv[3]);
        v2f m2 = __builtin_elementwise_max(sv[4], sv[5]);
        v2f m3 = __builtin_elementwise_max(sv[6], sv[7]);
        v2f m4 = __builtin_elementwise_max(sv[8], sv[9]);
        v2f m5 = __builtin_elementwise_max(sv[10], sv[11]);
        v2f m6 = __builtin_elementwise_max(sv[12], sv[13]);
        v2f m7 = __builtin_elementwise_max(sv[14], sv[15]);
        m0 = __builtin_elementwise_max(m0, m1);
        m2 = __builtin_elementwise_max(m2, m3);
        m4 = __builtin_elementwise_max(m4, m5);
        m6 = __builtin_elementwise_max(m6, m7);
        m0 = __builtin_elementwise_max(m0, m2);
        m4 = __builtin_elementwise_max(m4, m6);
        m = __builtin_elementwise_max(m0, m4);
      }
      float mv0 = m.x, mv1 = m.y;
      int ai0 = 0, ai1 = 0;
#pragma unroll
      for (int i = 15; i >= 0; --i) {     // downward: ends at smallest match
        ai0 = (sv[i].x == mv0) ? (i0 + i) : ai0;
        ai1 = (sv[i].y == mv1) ? (i0 + i) : ai1;
      }

      // combine across 8 row-groups: xor1, xor2, xor4 — all DPP
      {
        float pm0 = dpp_f<0xB1>(mv0), pm1 = dpp_f<0xB1>(mv1);
        int   pa0 = dpp_i<0xB1>(ai0), pa1 = dpp_i<0xB1>(ai1);
        float px  = dpp_f<0xB1>(S2.x), py = dpp_f<0xB1>(S2.y);
        if (pm0 > mv0 || (pm0 == mv0 && pa0 < ai0)) { mv0 = pm0; ai0 = pa0; }
        if (pm1 > mv1 || (pm1 == mv1 && pa1 < ai1)) { mv1 = pm1; ai1 = pa1; }
        S2.x += px; S2.y += py;
      }
      {
        float pm0 = dpp_f<0x4E>(mv0), pm1 = dpp_f<0x4E>(mv1);
        int   pa0 = dpp_i<0x4E>(ai0), pa1 = dpp_i<0x4E>(ai1);
        float px  = dpp_f<0x4E>(S2.x), py = dpp_f<0x4E>(S2.y);
        if (pm0 > mv0 || (pm0 == mv0 && pa0 < ai0)) { mv0 = pm0; ai0 = pa0; }
        if (pm1 > mv1 || (pm1 == mv1 && pa1 < ai1)) { mv1 = pm1; ai1 = pa1; }
        S2.x += px; S2.y += py;
      }
      {
        float pm0 = dpp_f<0x141>(mv0), pm1 = dpp_f<0x141>(mv1);
        int   pa0 = dpp_i<0x141>(ai0), pa1 = dpp_i<0x141>(ai1);
        float px  = dpp_f<0x141>(S2.x), py = dpp_f<0x141>(S2.y);
        if (pm0 > mv0 || (pm0 == mv0 && pa0 < ai0)) { mv0 = pm0; ai0 = pa0; }
        if (pm1 > mv1 || (pm1 == mv1 && pa1 < ai1)) { mv1 = pm1; ai1 = pa1; }
        S2.x += px; S2.y += py;
      }

      v2f em2 = emC[s];
      float evn0 = S2.x * __expf(em2.x) * r;
      float evn1 = S2.y * __expf(em2.y) * r;
      if (rg == 0) {
        *(v2f*)(avb[t & 1] + AIDX(j0)) = (v2f){mv0 + em2.x, mv1 + em2.y};
        *(v2f*)(evb[t & 1] + AIDX(j0)) = (v2f){evn0, evn1};
      }
      // accumulate bp bytes (uniform across rg)
      {
        unsigned int pk = ((unsigned int)ai0 | ((unsigned int)ai1 << 8))
                          << ((s & 1) * 16);
        if ((s >> 1) == 0) bq0 |= pk;
        else if ((s >> 1) == 1) bq1 |= pk;
        else if ((s >> 1) == 2) bq2 |= pk;
        else bq3 |= pk;
      }
      if (s == 3 || s == 7) {            // wmax for renorm (every 4 steps)
        float wm = fmaxf(evn0, evn1);
        wm = fmaxf(wm, dpp_f<0x140>(wm));   // xor8 (8-uniform)
        wm = fmaxf(wm, swz16_f(wm));        // xor16
        if ((tid & 31) == 0) wmax[tid >> 5] = wm;
      }
      __syncthreads();
    }
    pq0 = bq0; pq1 = bq1; pq2 = bq2; pq3 = bq3;
    pend_c = (tc - 1) >> 3;
#pragma unroll
    for (int s = 0; s < 8; ++s) emC[s] = emN[s];
  }
  if (pend_c >= 0 && rg == 1) {          // flush final (possibly partial) chunk
    uint4 v; v.x = pq0; v.y = pq1; v.z = pq2; v.w = pq3;
    *(uint4*)(bp + ((((b << 6) + pend_c) << 6) + cg) * 16) = v;
  }

  const float* avf = avb[(L - 1) & 1];
  const float* evf = evb[(L - 1) & 1];

  // ---- final argmax, ev sum, sequence score ----
  {
    float v = (tid < KK) ? avf[AIDX(tid)] : -3.4e38f;
    int idx = (tid < KK) ? tid : KK;
#pragma unroll
    for (int mm = 1; mm < 64; mm <<= 1) {
      float ov = __shfl_xor(v, mm);
      int oi = __shfl_xor(idx, mm);
      if (ov > v || (ov == v && oi < idx)) { v = ov; idx = oi; }
    }
    if ((tid & 63) == 0) { rv[tid >> 6] = v; ri[tid >> 6] = idx; }
  }
  {
    float ssum = (tid < KK) ? evf[AIDX(tid)] : 0.0f;
#pragma unroll
    for (int mm = 1; mm < 64; mm <<= 1) ssum += __shfl_xor(ssum, mm);
    if ((tid & 63) == 0) rs[tid >> 6] = ssum;
  }
  float sc = 0.0f;
  for (int tt2 = tid; tt2 < L; tt2 += 512) {
    int lab = labels[b * TT + tt2];
    sc += logits[(b * TT + tt2) * KK + lab];
    if (tt2 >= 1) sc += trans[labels[b * TT + tt2 - 1] * KK + lab];
  }
#pragma unroll
  for (int mm = 1; mm < 64; mm <<= 1) sc += __shfl_xor(sc, mm);
  if ((tid & 63) == 0) rsc[tid >> 6] = sc;
  __syncthreads();

  if (tid == 0) {
    float bv = rv[0]; int bi = ri[0];
    float es = rs[0]; float scf = rsc[0];
#pragma unroll
    for (int w = 1; w < 8; ++w) {
      if (rv[w] > bv || (rv[w] == bv && ri[w] < bi)) { bv = rv[w]; bi = ri[w]; }
      es += rs[w]; scf += rsc[w];
    }
    last_s = bi;
    negll[b] = (Cln + logf(es)) - scf;
  }
  __syncthreads();

  const int last = last_s;
  if (tid >= L - 1) tags[tid] = (unsigned char)last;
  __syncthreads();

  // ---- backtrace (wave 0): chunk-block prefetch + shfl extraction ----
  if (tid < 64 && L >= 2) {
    const int lane = tid;
    const uint4* bpv = (const uint4*)bp;
    int tag = last;
    int cTop = (L - 2) >> 3;
    uint4 q = bpv[(((b << 6) + cTop) << 6) + lane];
    for (int c = cTop; c >= 0; --c) {
      uint4 qn;
      if (c > 0) qn = bpv[(((b << 6) + (c - 1)) << 6) + lane];
      int sHi = (L - 2) - 8 * c; if (sHi > 7) sHi = 7;
#pragma unroll
      for (int s = 7; s >= 0; --s) {
        if (s <= sHi) {
          int word = (s >> 1) == 0 ? (int)q.x : (s >> 1) == 1 ? (int)q.y
                   : (s >> 1) == 2 ? (int)q.z : (int)q.w;
          unsigned int w = (unsigned int)__shfl(word, tag >> 1);
          tag = (int)((w >> ((((s & 1) << 1) | (tag & 1)) << 3)) & 255u);
          if (lane == 0) tags[8 * c + s] = (unsigned char)tag;
        }
      }
      q = qn;
    }
  }
  __syncthreads();

  pred_out[b * TT + tid] = (float)tags[tid];
}

__global__ void crf_loss_reduce(const float* __restrict__ negll, float* __restrict__ out) {
  int tid = threadIdx.x;
  float v = negll[tid];
#pragma unroll
  for (int m = 1; m < 64; m <<= 1) v += __shfl_xor(v, m);
  __shared__ float p[4];
  if ((tid & 63) == 0) p[tid >> 6] = v;
  __syncthreads();
  if (tid == 0) out[0] = p[0] + p[1] + p[2] + p[3];
}

extern "C" void kernel_launch(void* const* d_in, const int* in_sizes, int n_in,
                              void* d_out, int out_size, void* d_ws, size_t ws_size,
                              hipStream_t stream) {
  const float* logits   = (const float*)d_in[0];
  const int*   labels   = (const int*)d_in[1];
  const int*   seq_lens = (const int*)d_in[2];
  const float* trans    = (const float*)d_in[3];
  float* out = (float*)d_out;

  float* negll = (float*)d_ws;                          // 256 floats
  unsigned char* bp = (unsigned char*)d_ws + 1024;      // B*64*64*16 = 16.8 MB

  crf_forward<<<BB, 512, 0, stream>>>(logits, labels, seq_lens, trans,
                                      out + 1, negll, bp);
  crf_loss_reduce<<<1, 256, 0, stream>>>(negll, out);
}

// Round 4
// 499.060 us; speedup vs baseline: 1.7283x; 1.4049x over previous
//
#include <hip/hip_runtime.h>
#include <math.h>

#define BB 256
#define TT 512
#define KK 128
#define AIDX(i) ((i) + (((i) >> 5) << 2))

typedef float v2f __attribute__((ext_vector_type(2)));
typedef unsigned short u16v2 __attribute__((ext_vector_type(2)));

template<int CTRL>
__device__ __forceinline__ int dpp_i(int x) {
  return __builtin_amdgcn_update_dpp(x, x, CTRL, 0xF, 0xF, true);
}
template<int CTRL>
__device__ __forceinline__ float dpp_f(float x) {
  return __int_as_float(dpp_i<CTRL>(__float_as_int(x)));
}
__device__ __forceinline__ float swz16_f(float x) {
  return __int_as_float(__builtin_amdgcn_ds_swizzle(__float_as_int(x), 0x401F));
}
__device__ __forceinline__ int pkminu16(int a, int b) {
  u16v2 av = *(u16v2*)&a, bv = *(u16v2*)&b;
  u16v2 r = __builtin_elementwise_min(av, bv);
  return *(int*)&r;
}
// barrier that drains LDS only (not vmcnt) — keeps prefetch loads in flight
#define BARRIER_LGKM() asm volatile("s_waitcnt lgkmcnt(0)\ns_barrier" ::: "memory")

// DPP: 0xB1 quad_perm xor1, 0x4E quad_perm xor2, 0x141 row_half_mirror
// (acts as xor4 once values are quad-uniform), 0x140 row_mirror (xor8 when 8-uniform)

__global__ __launch_bounds__(512, 4) void crf_main(
    const float* __restrict__ logits,     // [B,T,K]
    const int* __restrict__ labels,       // [B,T]
    const int* __restrict__ seq_lens,     // [B]
    const float* __restrict__ trans,      // [K,K]
    float* __restrict__ pred_out,         // [B,T] as float (d_out+1)
    float* __restrict__ negll,            // [B] in ws
    unsigned char* __restrict__ bp)       // [B][128 chunk][64 cg][8B] in ws
{
  const int tid = threadIdx.x;
  const int cg = tid >> 3, rg = tid & 7;
  const int j0 = cg * 2, i0 = rg * 16;

  if (blockIdx.x < BB) {
    // ================= VITERBI PATH =================
    const int b = blockIdx.x;
    const int L = seq_lens[b];
    __shared__ __align__(16) float av[2][144];
    __shared__ unsigned char tags[TT];
    __shared__ float rv[8]; __shared__ int ri[8];
    __shared__ int last_s;

    v2f tv[16];
#pragma unroll
    for (int ii = 0; ii < 16; ++ii)
      tv[ii] = *(const v2f*)&trans[(i0 + ii) * KK + j0];

    if (tid < KK) av[0][AIDX(tid)] = logits[(b * TT) * KK + tid];

    v2f emC[4], emN[4];
#pragma unroll
    for (int s = 0; s < 4; ++s) {
      int t2 = 1 + s; if (t2 > L - 1) t2 = (L > 1) ? (L - 1) : 0;
      emC[s] = *(const v2f*)&logits[(b * TT + t2) * KK + j0];
    }
    __syncthreads();

    unsigned int pw0 = 0, pw1 = 0; int pend_c = -1;

    for (int tc = 1; tc < L; tc += 4) {
#pragma unroll
      for (int s = 0; s < 4; ++s) {
        int t2 = tc + 4 + s; if (t2 > L - 1) t2 = L - 1;
        emN[s] = *(const v2f*)&logits[(b * TT + t2) * KK + j0];
      }
      if (pend_c >= 0 && rg == 1) {
        *(uint2*)(bp + (((b << 7) + pend_c) << 9) + (cg << 3)) =
            make_uint2(pw0, pw1);
      }
      unsigned int w0 = 0, w1 = 0;
#pragma unroll
      for (int s = 0; s < 4; ++s) {
        const int t = tc + s;
        if (t >= L) break;
        const float4* avr = (const float4*)(av[(t & 1) ^ 1] + AIDX(i0));
        v2f sv[16];
#pragma unroll
        for (int q = 0; q < 4; ++q) {
          float4 a4 = avr[q];
#pragma unroll
          for (int c = 0; c < 4; ++c) {
            float a = (c == 0) ? a4.x : (c == 1) ? a4.y : (c == 2) ? a4.z : a4.w;
            sv[q * 4 + c] = (v2f){a, a} + tv[q * 4 + c];   // exact IEEE adds
          }
        }
        // in-thread max tree (exact; max is order-insensitive)
        v2f m;
        {
          v2f m0 = __builtin_elementwise_max(sv[0], sv[1]);
          v2f m1 = __builtin_elementwise_max(sv[2], sv[3]);
          v2f m2 = __builtin_elementwise_max(sv[4], sv[5]);
          v2f m3 = __builtin_elementwise_max(sv[6], sv[7]);
          v2f m4 = __builtin_elementwise_max(sv[8], sv[9]);
          v2f m5 = __builtin_elementwise_max(sv[10], sv[11]);
          v2f m6 = __builtin_elementwise_max(sv[12], sv[13]);
          v2f m7 = __builtin_elementwise_max(sv[14], sv[15]);
          m0 = __builtin_elementwise_max(m0, m1);
          m2 = __builtin_elementwise_max(m2, m3);
          m4 = __builtin_elementwise_max(m4, m5);
          m6 = __builtin_elementwise_max(m6, m7);
          m0 = __builtin_elementwise_max(m0, m2);
          m4 = __builtin_elementwise_max(m4, m6);
          m = __builtin_elementwise_max(m0, m4);
        }
        // global max across the 8 row-groups (xor1, xor2, xor4) — all DPP
        {
          v2f o;
          o.x = dpp_f<0xB1>(m.x); o.y = dpp_f<0xB1>(m.y);
          m = __builtin_elementwise_max(m, o);
          o.x = dpp_f<0x4E>(m.x); o.y = dpp_f<0x4E>(m.y);
          m = __builtin_elementwise_max(m, o);
          o.x = dpp_f<0x141>(m.x); o.y = dpp_f<0x141>(m.y);
          m = __builtin_elementwise_max(m, o);
        }
        // first-index recovery: downward eq-scan, then packed u16 min
        int ai0 = 0xFFFF, ai1 = 0xFFFF;
#pragma unroll
        for (int i = 15; i >= 0; --i) {
          ai0 = (sv[i].x == m.x) ? (i0 + i) : ai0;
          ai1 = (sv[i].y == m.y) ? (i0 + i) : ai1;
        }
        int aip = ai0 | (ai1 << 16);
        aip = pkminu16(aip, dpp_i<0xB1>(aip));
        aip = pkminu16(aip, dpp_i<0x4E>(aip));
        aip = pkminu16(aip, dpp_i<0x141>(aip));

        v2f em2 = emC[s];
        if (rg == 0)
          *(v2f*)(av[t & 1] + AIDX(j0)) = m + em2;
        unsigned int pk = ((unsigned int)aip & 0xFFu) |
                          (((unsigned int)aip >> 8) & 0xFF00u);
        unsigned int sh = pk << ((s & 1) * 16);
        if (s < 2) w0 |= sh; else w1 |= sh;
        BARRIER_LGKM();
      }
      pw0 = w0; pw1 = w1; pend_c = (tc - 1) >> 2;
#pragma unroll
      for (int s = 0; s < 4; ++s) emC[s] = emN[s];
    }
    if (pend_c >= 0 && rg == 1) {
      *(uint2*)(bp + (((b << 7) + pend_c) << 9) + (cg << 3)) =
          make_uint2(pw0, pw1);
    }

    const float* avf = av[(L - 1) & 1];
    {
      float v = (tid < KK) ? avf[AIDX(tid)] : -3.4e38f;
      int idx = (tid < KK) ? tid : KK;
#pragma unroll
      for (int mm = 1; mm < 64; mm <<= 1) {
        float ov = __shfl_xor(v, mm);
        int oi = __shfl_xor(idx, mm);
        if (ov > v || (ov == v && oi < idx)) { v = ov; idx = oi; }
      }
      if ((tid & 63) == 0) { rv[tid >> 6] = v; ri[tid >> 6] = idx; }
    }
    __syncthreads();
    if (tid == 0) {
      float bv = rv[0]; int bi = ri[0];
#pragma unroll
      for (int w = 1; w < 8; ++w)
        if (rv[w] > bv || (rv[w] == bv && ri[w] < bi)) { bv = rv[w]; bi = ri[w]; }
      last_s = bi;
    }
    __syncthreads();
    const int last = last_s;
    if (tid >= L - 1 && tid < TT) tags[tid] = (unsigned char)last;
    __syncthreads();

    if (tid < 64 && L >= 2) {
      const uint2* bpv = (const uint2*)bp;
      int tag = last;
      int cTop = (L - 2) >> 2;
      uint2 q = bpv[(((b << 7) + cTop) << 6) + tid];
      for (int c = cTop; c >= 0; --c) {
        uint2 qn;
        if (c > 0) qn = bpv[(((b << 7) + (c - 1)) << 6) + tid];
        int sHi = (L - 2) - 4 * c; if (sHi > 3) sHi = 3;
#pragma unroll
        for (int s = 3; s >= 0; --s) {
          if (s <= sHi) {
            int word = (s < 2) ? (int)q.x : (int)q.y;
            unsigned int w = (unsigned int)__shfl(word, tag >> 1);
            tag = (int)((w >> ((((s & 1) << 1) | (tag & 1)) << 3)) & 255u);
            if (tid == 0) tags[4 * c + s] = (unsigned char)tag;
          }
        }
        q = qn;
      }
    }
    __syncthreads();
    pred_out[b * TT + tid] = (float)tags[tid];

  } else {
    // ================= FORWARD (log-norm) PATH =================
    const int b = blockIdx.x - BB;
    const int L = seq_lens[b];
    __shared__ __align__(16) float ev[2][144];
    __shared__ __align__(16) float wmax[16];
    __shared__ float rs[8]; __shared__ float rsc[8];

    v2f tw[16];
#pragma unroll
    for (int ii = 0; ii < 16; ++ii) {
      v2f tr = *(const v2f*)&trans[(i0 + ii) * KK + j0];
      tw[ii].x = __expf(tr.x);
      tw[ii].y = __expf(tr.y);
    }
    if (tid < KK) ev[0][AIDX(tid)] = __expf(logits[(b * TT) * KK + tid]);
    if (tid < 16) wmax[tid] = 1.0f;

    v2f emC[4], emN[4];
#pragma unroll
    for (int s = 0; s < 4; ++s) {
      int t2 = 1 + s; if (t2 > L - 1) t2 = (L > 1) ? (L - 1) : 0;
      emC[s] = *(const v2f*)&logits[(b * TT + t2) * KK + j0];
    }
    __syncthreads();

    float Cln = 0.0f;
    for (int tc = 1; tc < L; tc += 4) {
#pragma unroll
      for (int s = 0; s < 4; ++s) {
        int t2 = tc + 4 + s; if (t2 > L - 1) t2 = L - 1;
        emN[s] = *(const v2f*)&logits[(b * TT + t2) * KK + j0];
      }
      // renorm factor (exact pow2), once per 4-step chunk
      float r;
      {
        float4 w0 = *(const float4*)&wmax[0];
        float4 w1 = *(const float4*)&wmax[4];
        float4 w2 = *(const float4*)&wmax[8];
        float4 w3 = *(const float4*)&wmax[12];
        float U = fmaxf(fmaxf(fmaxf(w0.x, w0.y), fmaxf(w0.z, w0.w)),
                        fmaxf(fmaxf(w1.x, w1.y), fmaxf(w1.z, w1.w)));
        U = fmaxf(U, fmaxf(fmaxf(fmaxf(w2.x, w2.y), fmaxf(w2.z, w2.w)),
                           fmaxf(fmaxf(w3.x, w3.y), fmaxf(w3.z, w3.w))));
        int ex = (__float_as_int(U) >> 23) & 255;
        r = __int_as_float((254 - ex) << 23);
        Cln += (float)(ex - 127) * 0.6931471805599453f;
      }
#pragma unroll
      for (int s = 0; s < 4; ++s) {
        const int t = tc + s;
        if (t >= L) break;
        const float4* evr = (const float4*)(ev[(t & 1) ^ 1] + AIDX(i0));
        v2f S2 = {0.0f, 0.0f};
#pragma unroll
        for (int q = 0; q < 4; ++q) {
          float4 e4 = evr[q];
#pragma unroll
          for (int c = 0; c < 4; ++c) {
            float e = (c == 0) ? e4.x : (c == 1) ? e4.y : (c == 2) ? e4.z : e4.w;
            S2 += (v2f){e, e} * tw[q * 4 + c];   // pk_fma
          }
        }
        {
          v2f o;
          o.x = dpp_f<0xB1>(S2.x); o.y = dpp_f<0xB1>(S2.y); S2 += o;
          o.x = dpp_f<0x4E>(S2.x); o.y = dpp_f<0x4E>(S2.y); S2 += o;
          o.x = dpp_f<0x141>(S2.x); o.y = dpp_f<0x141>(S2.y); S2 += o;
        }
        v2f em2 = emC[s];
        float evn0 = S2.x * __expf(em2.x);
        float evn1 = S2.y * __expf(em2.y);
        if (s == 0) { evn0 *= r; evn1 *= r; }
        if (rg == 0)
          *(v2f*)(ev[t & 1] + AIDX(j0)) = (v2f){evn0, evn1};
        if (s == 3) {
          float wm = fmaxf(evn0, evn1);
          wm = fmaxf(wm, dpp_f<0x140>(wm));   // xor8 (values 8-uniform)
          wm = fmaxf(wm, swz16_f(wm));        // xor16
          if ((tid & 31) == 0) wmax[tid >> 5] = wm;
        }
        BARRIER_LGKM();
      }
#pragma unroll
      for (int s = 0; s < 4; ++s) emC[s] = emN[s];
    }

    const float* evf = ev[(L - 1) & 1];
    {
      float ssum = (tid < KK) ? evf[AIDX(tid)] : 0.0f;
#pragma unroll
      for (int mm = 1; mm < 64; mm <<= 1) ssum += __shfl_xor(ssum, mm);
      if ((tid & 63) == 0) rs[tid >> 6] = ssum;
    }
    float sc = 0.0f;
    for (int tt2 = tid; tt2 < L; tt2 += 512) {
      int lab = labels[b * TT + tt2];
      sc += logits[(b * TT + tt2) * KK + lab];
      if (tt2 >= 1) sc += trans[labels[b * TT + tt2 - 1] * KK + lab];
    }
#pragma unroll
    for (int mm = 1; mm < 64; mm <<= 1) sc += __shfl_xor(sc, mm);
    if ((tid & 63) == 0) rsc[tid >> 6] = sc;
    __syncthreads();
    if (tid == 0) {
      float es = rs[0]; float scf = rsc[0];
#pragma unroll
      for (int w = 1; w < 8; ++w) { es += rs[w]; scf += rsc[w]; }
      negll[b] = (Cln + logf(es)) - scf;
    }
  }
}

__global__ void crf_loss_reduce(const float* __restrict__ negll, float* __restrict__ out) {
  int tid = threadIdx.x;
  float v = negll[tid];
#pragma unroll
  for (int m = 1; m < 64; m <<= 1) v += __shfl_xor(v, m);
  __shared__ float p[4];
  if ((tid & 63) == 0) p[tid >> 6] = v;
  __syncthreads();
  if (tid == 0) out[0] = p[0] + p[1] + p[2] + p[3];
}

extern "C" void kernel_launch(void* const* d_in, const int* in_sizes, int n_in,
                              void* d_out, int out_size, void* d_ws, size_t ws_size,
                              hipStream_t stream) {
  const float* logits   = (const float*)d_in[0];
  const int*   labels   = (const int*)d_in[1];
  const int*   seq_lens = (const int*)d_in[2];
  const float* trans    = (const float*)d_in[3];
  float* out = (float*)d_out;

  float* negll = (float*)d_ws;                          // 256 floats
  unsigned char* bp = (unsigned char*)d_ws + 1024;      // B*128*64*8 = 16.8 MB

  crf_main<<<2 * BB, 512, 0, stream>>>(logits, labels, seq_lens, trans,
                                       out + 1, negll, bp);
  crf_loss_reduce<<<1, 256, 0, stream>>>(negll, out);
}